// Round 9
// baseline (255.606 us; speedup 1.0000x reference)
//
#include <hip/hip_runtime.h>

#define N_NODES_C 50000
#define FDIM 64
#define EPS_C 1e-5f

#define PARTS 4             // 50000/4 = 12500 exact
#define NPP 12500
#define SLICE (3 * NPP)     // 37500 floats = 150 KB dynamic LDS -> 1 block/CU
#define BPERP 64            // grid = 4*64 = 256 blocks = 1/CU
#define SCAT_BLK 1024
#define SCAT_GRID (PARTS * BPERP)

typedef float vfloat4 __attribute__((ext_vector_type(4)));

__device__ __forceinline__ void nt_store_f4(float4* p, float x, float y, float z, float w) {
    vfloat4 v = { x, y, z, w };
    __builtin_nontemporal_store(v, (vfloat4*)p);
}

// one edge: conditional LDS-atomic triple
#define EDGE_ACC(D, SV, QV)                                            \
    { unsigned l_ = (unsigned)((D) - lo);                              \
      if (l_ < NPP) { atomicAdd(&sm[l_], (SV));                        \
                      atomicAdd(&sm[NPP + l_], (QV));                  \
                      atomicAdd(&sm[2 * NPP + l_], 1.0f); } }

// ---------------------------------------------------------------------------
// Pass A: per-edge partials. Dense stream of e (normal loads -> e allocates
// in L3 for norm's re-read); nt-store the partials (no reuse pollution).
// ---------------------------------------------------------------------------
__global__ void __launch_bounds__(256)
partial_kernel(const float4* __restrict__ e4, float2* __restrict__ partials,
               int nEdges) {
    const int total = nEdges * 16;
    const int stride = gridDim.x * blockDim.x;   // %16==0 -> groups aligned
    for (int idx = blockIdx.x * blockDim.x + threadIdx.x; idx < total; idx += stride) {
        float4 v = e4[idx];
        float sum = (v.x + v.y) + (v.z + v.w);
        float sq  = (v.x * v.x + v.y * v.y) + (v.z * v.z + v.w * v.w);
#pragma unroll
        for (int m = 1; m < 16; m <<= 1) {
            sum += __shfl_xor(sum, m);
            sq  += __shfl_xor(sq,  m);
        }
        if ((idx & 15) == 0) {
            unsigned long long bits;
            float2 pq = make_float2(sum, sq);
            __builtin_memcpy(&bits, &pq, 8);
            __builtin_nontemporal_store(bits, (unsigned long long*)(partials + (idx >> 4)));
        }
    }
}

// ---------------------------------------------------------------------------
// Pass B: scatter cache-resident partials into partitioned LDS stats.
// PARTS=4 with a 150 KB dynamic-LDS slice: only a 4x rescan of dst+partials
// (77 MB total, L2/L3-served regardless of XCD block placement).
// ---------------------------------------------------------------------------
__global__ void __launch_bounds__(SCAT_BLK)
scatter_kernel(const int* __restrict__ dst, const float2* __restrict__ partials,
               float* __restrict__ acc, int nEdges) {
    extern __shared__ float sm[];               // SLICE floats = 150 KB
    const int tid = threadIdx.x;
    for (int i = tid; i < SLICE; i += SCAT_BLK) sm[i] = 0.0f;
    __syncthreads();

    const int p  = blockIdx.x / BPERP;
    const int b  = blockIdx.x % BPERP;
    const int lo = p * NPP;

    const int step = BPERP * SCAT_BLK * 4;      // 262144 edges per sweep
    for (int i0 = (b * SCAT_BLK + tid) * 4; i0 < nEdges; i0 += step) {
        if (i0 + 3 < nEdges) {
            int4   d4  = *(const int4*)(dst + i0);
            float4 p01 = *(const float4*)(partials + i0);
            float4 p23 = *(const float4*)(partials + i0 + 2);
            EDGE_ACC(d4.x, p01.x, p01.y); EDGE_ACC(d4.y, p01.z, p01.w);
            EDGE_ACC(d4.z, p23.x, p23.y); EDGE_ACC(d4.w, p23.z, p23.w);
        } else {
            for (int i = i0; i < nEdges; ++i) {
                float2 pq = partials[i];
                EDGE_ACC(dst[i], pq.x, pq.y);
            }
        }
    }
    __syncthreads();
    float* __restrict__ outp = acc + (size_t)blockIdx.x * SLICE;
    for (int i = tid; i < SLICE; i += SCAT_BLK) {
        __builtin_nontemporal_store(sm[i], outp + i);   // no L3 pollution
    }
}

// ---------------------------------------------------------------------------
// Pass C: sum the BPERP per-block copies; mean + 1/(std+eps), unbiased (n-1).
// ---------------------------------------------------------------------------
__global__ void __launch_bounds__(256)
reduce_finalize_kernel(const float* __restrict__ acc, float2* __restrict__ stats,
                       int nNodes) {
    int n = blockIdx.x * blockDim.x + threadIdx.x;
    if (n >= nNodes) return;
    int p = n / NPP, local = n - p * NPP;
    const float* bptr = acc + (size_t)(p * BPERP) * SLICE + local;
    float s = 0.f, q = 0.f, dg = 0.f;
#pragma unroll 8
    for (int bb = 0; bb < BPERP; ++bb, bptr += SLICE) {
        s  += bptr[0];
        q  += bptr[NPP];
        dg += bptr[2 * NPP];
    }
    float cnt  = dg * (float)FDIM;
    float safe = fmaxf(cnt, 1.0f);
    float mean = s / safe;
    float var  = (q - cnt * mean * mean) / fmaxf(cnt - 1.0f, 1.0f);
    float stdv = sqrtf(fmaxf(var, 0.0f));
    stats[n] = make_float2(mean, 1.0f / (stdv + EPS_C));
}

// ---------------------------------------------------------------------------
// Pass D: normalize. Reverse iteration order (read e's L3-resident tail
// first) + nt-stores for out (keep out's 410 MB from evicting e in L3).
// ---------------------------------------------------------------------------
__global__ void __launch_bounds__(256)
norm_kernel(const float4* __restrict__ e4, const int* __restrict__ dst,
            const float2* __restrict__ stats,
            const float4* __restrict__ gamma4, const float4* __restrict__ beta4,
            float4* __restrict__ out4, int nEdges) {
    const int total  = nEdges * 16;
    const int stride = gridDim.x * blockDim.x;   // %16==0
    const int gtid   = blockIdx.x * blockDim.x + threadIdx.x;
    const int sub    = gtid & 15;
    const float4 g = gamma4[sub];
    const float4 b = beta4[sub];
    const int nIter = (total + stride - 1) / stride;
    for (int it = nIter - 1; it >= 0; --it) {
        int idx = it * stride + gtid;
        if (idx >= total) continue;
        float2 mi = stats[dst[idx >> 4]];
        float4 v  = e4[idx];
        nt_store_f4(out4 + idx,
                    g.x * (v.x - mi.x) * mi.y + b.x,
                    g.y * (v.y - mi.x) * mi.y + b.y,
                    g.z * (v.z - mi.x) * mi.y + b.z,
                    g.w * (v.w - mi.x) * mi.y + b.w);
    }
}

extern "C" void kernel_launch(void* const* d_in, const int* in_sizes, int n_in,
                              void* d_out, int out_size, void* d_ws, size_t ws_size,
                              hipStream_t stream) {
    const float* e     = (const float*)d_in[0];
    const float* gamma = (const float*)d_in[1];
    const float* beta  = (const float*)d_in[2];
    const int*   dst   = (const int*)d_in[3];
    const int nEdges = in_sizes[3];
    const int nNodes = N_NODES_C;

    // d_ws layout (all regions fully overwritten every call -> no memset):
    //   acc      [SCAT_GRID][SLICE] = 38.4 MB
    //   stats    [N] float2         =  0.4 MB
    //   partials [E] float2         = 12.8 MB
    float*  acc      = (float*)d_ws;
    float2* stats    = (float2*)(acc + (size_t)SCAT_GRID * SLICE);
    float2* partials = stats + nNodes;

    // allow 150 KB dynamic LDS for the scatter (capture-safe host call)
    hipFuncSetAttribute((const void*)scatter_kernel,
                        hipFuncAttributeMaxDynamicSharedMemorySize,
                        SLICE * (int)sizeof(float));

    partial_kernel<<<2048, 256, 0, stream>>>((const float4*)e, partials, nEdges);
    scatter_kernel<<<SCAT_GRID, SCAT_BLK, SLICE * sizeof(float), stream>>>(
        dst, partials, acc, nEdges);
    reduce_finalize_kernel<<<(nNodes + 255) / 256, 256, 0, stream>>>(acc, stats, nNodes);
    norm_kernel<<<2048, 256, 0, stream>>>(
        (const float4*)e, dst, stats,
        (const float4*)gamma, (const float4*)beta,
        (float4*)d_out, nEdges);
}